// Round 11
// baseline (5812.324 us; speedup 1.0000x reference)
//
#include <hip/hip_runtime.h>
#include <stdint.h>
#include <stddef.h>

typedef unsigned short ushort_t;
typedef float f32x4 __attribute__((ext_vector_type(4)));
typedef short short8 __attribute__((ext_vector_type(8)));

#define NB 16384
#define DIMX 256
#define HIDX 1024
#define DTC (-0.1f)

__device__ __forceinline__ unsigned short f2bf_bits(float f){
  unsigned int u = __float_as_uint(f);
  unsigned int r = (u + 0x7FFFu + ((u >> 16) & 1u)) >> 16;
  return (unsigned short)r;
}
__device__ __forceinline__ float bf2f_bits(unsigned short s){
  return __uint_as_float(((unsigned int)s) << 16);
}
__device__ __forceinline__ float fast_tanh(float x){
  float a = fabsf(x);
  float e = __expf(a + a);
  float r = 1.0f - 2.0f / (e + 1.0f);
  return copysignf(r, x);
}
__device__ __forceinline__ void gload16(const void* g, void* l){
  __builtin_amdgcn_global_load_lds(
      (const __attribute__((address_space(1))) void*)g,
      (__attribute__((address_space(3))) void*)l, 16, 0, 0);
}
// counted vmcnt wait (T4) — literal immediates via if-constexpr table
template<int N> __device__ __forceinline__ void wait_vmcnt(){
  if constexpr (N == 0)      asm volatile("s_waitcnt vmcnt(0)" ::: "memory");
  else if constexpr (N == 3) asm volatile("s_waitcnt vmcnt(3)" ::: "memory");
  else if constexpr (N == 4) asm volatile("s_waitcnt vmcnt(4)" ::: "memory");
  else if constexpr (N == 6) asm volatile("s_waitcnt vmcnt(6)" ::: "memory");
  else if constexpr (N == 8) asm volatile("s_waitcnt vmcnt(8)" ::: "memory");
  else static_assert(N == 0, "unsupported vmcnt");
}
// T2 swizzle, 64-col (128B) rows. LDS[r*64 + (c ^ ((r&7)<<3))] = elem (r,c).
__device__ __forceinline__ int ldsx(int r, int c){
  return r * 64 + (c ^ ((r & 7) << 3));
}
// T2 swizzle, 32-col (64B) rows (PIPE=3): block b = g ^ (r&3) ^ ((r>>2)&3);
// per 16-row stripe each (parity,16B-slot) gets 2 rows — free 2-way (m136).
__device__ __forceinline__ int ldsx32(int r, int g){
  return r * 32 + ((g ^ (r & 3) ^ ((r >> 2) & 3)) << 3);
}

// -------- weight prep: fp32 -> bf16; transposed [N][K] layouts + W3n --------
__global__ void prep_weights(const float* __restrict__ W1, const float* __restrict__ W2,
                             const float* __restrict__ W3,
                             ushort_t* __restrict__ W1at, ushort_t* __restrict__ W2t,
                             ushort_t* __restrict__ W3t, ushort_t* __restrict__ W3n){
  int i = blockIdx.x * blockDim.x + threadIdx.x;
  const int T1 = 1024 * 256, T2 = 1024 * 1024, T3 = 256 * 1024, T4 = 1024 * 256;
  if (i < T1){
    int n = i >> 8, k = i & 255;                 // W1at[n][k] = W1[k][n]
    W1at[i] = f2bf_bits(W1[k * 1024 + n]);
  } else if (i < T1 + T2){
    int j = i - T1; int n = j >> 10, k = j & 1023; // W2t[n][k] = W2[k][n]
    W2t[j] = f2bf_bits(W2[k * 1024 + n]);
  } else if (i < T1 + T2 + T3){
    int j = i - T1 - T2; int n = j >> 10, k = j & 1023; // W3t[n][k] = W3[k][n]
    W3t[j] = f2bf_bits(W3[k * 256 + n]);
  } else if (i < T1 + T2 + T3 + T4){
    int j = i - T1 - T2 - T3;                    // W3n[h][d] = W3[h][d] (g-GEMM B)
    W3n[j] = f2bf_bits(W3[j]);
  }
}

// ----------- noise = sin(1000*(x@proj))*sqrt2 (fp32!), state init -----------
__global__ void noise_init(const float* __restrict__ x, const float* __restrict__ proj,
                           ushort_t* __restrict__ noise_bf,
                           float* __restrict__ xt, ushort_t* __restrict__ xcbf,
                           float* __restrict__ ljt){
  const int r0 = blockIdx.x * 8;
  const int j = threadIdx.x;   // 256 threads = one output col each
  __shared__ float xrow[8][256];
  #pragma unroll
  for (int r = 0; r < 8; ++r) xrow[r][j] = x[(size_t)(r0 + r) * 256 + j];
  __syncthreads();
  float s[8] = {0.f,0.f,0.f,0.f,0.f,0.f,0.f,0.f};
  for (int k = 0; k < 256; ++k){
    float p = proj[k * 256 + j];
    #pragma unroll
    for (int r = 0; r < 8; ++r) s[r] = fmaf(xrow[r][k], p, s[r]);
  }
  #pragma unroll
  for (int r = 0; r < 8; ++r){
    float nz = sinf(s[r] * 1000.0f) * 1.41421356237f;
    size_t idx = (size_t)(r0 + r) * 256 + j;
    noise_bf[idx] = f2bf_bits(nz);
    float xv = xrow[r][j];
    xt[idx] = xv;
    xcbf[idx] = f2bf_bits(xv);
  }
  if (j < 8) ljt[r0 + j] = 0.0f;
}

// ---- GEMM template. PIPE=0: simple 2-barrier loop (memory-bound EPIs).
// PIPE=1: depth-2 prefetch dbuf, BK=64, counted vmcnt (85µs L2 schedule).
// PIPE=3: same skeleton at BK=32 with halved wave-tile (32x64) — acc regs
// 128->64 so regalloc fits 128 total => 4 waves/SIMD (2 blocks/CU). The
// occupancy experiment: co-resident block covers barrier drains (m114).
// C[M,N] = A[M,K] @ W[K,N], W stored transposed [N][K] bf16, A row-major bf16.
// 8 waves as WGM(M) x (8/WGM)(N).
// DUAL: 0 = single GEMM; 1 = dual (A2 staged from global, e.g. dh1).
// EPI: 0 = store bf16 (dz1/g); 1 = layer1 (tanh -> h1, (1-h^2)*dz1 -> dh1);
// 2 = layer2 (tanh -> h2 + fused trace into ljt); 3 = layer3 (RK4 update).
// Lessons: r3 = no pipe on memory-bound EPIs; r4/m141 = no sched_barrier(0);
// r6 = no in-K-loop tangent recompute; r8/r9 = phase-split loses at NT=16 +
// dual traffic, and reads before the post-vmcnt barrier are a RACE (vmcnt
// covers only the issuing wave's loads).
template<int BM, int BN, int WGM, int K, int DUAL, int EPI, int PIPE>
__launch_bounds__(512, (PIPE == 3) ? 4 : 2)
__global__ void gemm_kernel(const ushort_t* __restrict__ A1, const ushort_t* __restrict__ A2,
                            const ushort_t* __restrict__ Wt,
                            ushort_t* __restrict__ out1, ushort_t* __restrict__ out2,
                            const float* __restrict__ bias, const float* __restrict__ w1trow,
                            float tval,
                            const ushort_t* __restrict__ dz1,
                            const ushort_t* __restrict__ gtr,
                            float* __restrict__ xt, float* __restrict__ vacc,
                            ushort_t* __restrict__ xcbf,
                            float* __restrict__ ljt, float wdt6, int rk){
  constexpr int WGN = 8 / WGM;
  constexpr int WM = BM / WGM, WN = BN / WGN;
  constexpr int M_REP = WM / 16, N_REP = WN / 16;
  constexpr int ATILES = DUAL ? 2 : 1;
  constexpr int ROWS = ATILES * BM + BN;

  const int m0 = blockIdx.x * BM;
  const int n0 = blockIdx.y * BN;
  const int tid = threadIdx.x;
  const int lane = tid & 63;
  const int wid = tid >> 6;
  const int wr = wid / WGN;
  const int wc = wid % WGN;

  f32x4 acc1[M_REP][N_REP] = {};
  f32x4 acc2[M_REP][N_REP] = {};

  if constexpr (PIPE == 3){
    // -------- BK=32 dbuf pipeline, wave-tile 32x64, 2 blocks/CU target -----
    constexpr int NT = K / 32;
    constexpr int CH = ROWS / 16;               // 1KB chunks (16r x 32c) per tile
    constexpr int CH_PW = CH / 8;               // 3 for 128/128 dual
    constexpr int BUF_E = ROWS * 32;
    static_assert(CH_PW * 8 == CH, "chunk split");
    __shared__ __align__(16) ushort_t lds[2 * BUF_E];   // 48 KB

    const int srow = lane >> 2;                 // 0..15 row-in-chunk
    const int scb  = (lane & 3) ^ (srow & 3) ^ ((srow >> 2) & 3);
    const int scol = scb << 3;                  // pre-swizzled source colblock
    const ushort_t* srcb[CH_PW];
    #pragma unroll
    for (int c = 0; c < CH_PW; ++c){
      const int gr = (wid * CH_PW + c) * 16 + srow;   // row in [A1|A2|B] space
      if (gr < BM)               srcb[c] = A1 + (size_t)(m0 + gr) * K + scol;
      else if (DUAL && gr < 2 * BM) srcb[c] = A2 + (size_t)(m0 + gr - BM) * K + scol;
      else                       srcb[c] = Wt + (size_t)(n0 + gr - ATILES * BM) * K + scol;
    }
    auto do_stage = [&](int buf, int t){
      ushort_t* dst = lds + buf * BUF_E + (wid * CH_PW) * 512;
      #pragma unroll
      for (int c = 0; c < CH_PW; ++c)
        gload16(srcb[c] + t * 32, dst + c * 512);
    };
    auto compute = [&](int buf){
      const ushort_t* base = lds + buf * BUF_E;
      const int g = lane >> 4;                  // col-block 0..3
      const int lro = lane & 15;
      short8 a1f[M_REP], a2f[M_REP], bfr[N_REP];
      #pragma unroll
      for (int m = 0; m < M_REP; ++m){
        const int r = wr * WM + m * 16 + lro;
        a1f[m] = *(const short8*)(base + ldsx32(r, g));
        a2f[m] = *(const short8*)(base + ldsx32(BM + r, g));
      }
      #pragma unroll
      for (int n = 0; n < N_REP; ++n){
        const int rn = ATILES * BM + wc * WN + n * 16 + lro;
        bfr[n] = *(const short8*)(base + ldsx32(rn, g));
      }
      #pragma unroll
      for (int m = 0; m < M_REP; ++m){
        #pragma unroll
        for (int n = 0; n < N_REP; ++n){
          acc1[m][n] = __builtin_amdgcn_mfma_f32_16x16x32_bf16(a1f[m], bfr[n], acc1[m][n], 0, 0, 0);
          acc2[m][n] = __builtin_amdgcn_mfma_f32_16x16x32_bf16(a2f[m], bfr[n], acc2[m][n], 0, 0, 0);
        }
      }
    };
    // PIPE-1 skeleton (vmcnt(own) -> barrier -> reads: race-safe per r9)
    do_stage(0, 0);
    do_stage(1, 1);
    for (int t = 0; t < NT - 2; ++t){
      wait_vmcnt<CH_PW>();
      __builtin_amdgcn_s_barrier();
      compute(t & 1);
      asm volatile("s_waitcnt lgkmcnt(0)" ::: "memory");
      __builtin_amdgcn_s_barrier();
      do_stage(t & 1, t + 2);
    }
    wait_vmcnt<CH_PW>();
    __builtin_amdgcn_s_barrier();
    compute(NT & 1);
    wait_vmcnt<0>();
    __builtin_amdgcn_s_barrier();
    compute((NT - 1) & 1);
  } else {
    constexpr int BK = 64;
    constexpr int CH_A = BM / 8;
    constexpr int CH_TOT = ATILES * CH_A + BN / 8;
    constexpr int CH_PW = CH_TOT / 8;
    constexpr int BUF_E = ROWS * BK;
    constexpr int NBUF = PIPE ? 2 : 1;
    constexpr int NK = K / BK;
    __shared__ __align__(16) ushort_t lds[NBUF * BUF_E];

    const int srow = lane >> 3;
    const int scol = ((lane & 7) ^ srow) * 8;
    const ushort_t* srcb[CH_PW];
    #pragma unroll
    for (int c = 0; c < CH_PW; ++c){
      const int ch = wid * CH_PW + c;
      if (ch < CH_A)
        srcb[c] = A1 + (size_t)(m0 + ch * 8 + srow) * K + scol;
      else if (DUAL && ch < 2 * CH_A)
        srcb[c] = A2 + (size_t)(m0 + (ch - CH_A) * 8 + srow) * K + scol;
      else
        srcb[c] = Wt + (size_t)(n0 + (ch - ATILES * CH_A) * 8 + srow) * K + scol;
    }
    auto do_stage = [&](int buf, int ks){
      ushort_t* dst = lds + buf * BUF_E + (wid * CH_PW) * 512;
      const int k0 = ks * BK;
      #pragma unroll
      for (int c = 0; c < CH_PW; ++c)
        gload16(srcb[c] + k0, dst + c * 512);
    };
    auto compute = [&](int buf){
      const ushort_t* ldsA1 = lds + buf * BUF_E;
      const ushort_t* ldsA2 = ldsA1 + BM * BK;
      const ushort_t* ldsB  = ldsA1 + ATILES * BM * BK;
      #pragma unroll
      for (int kk = 0; kk < 2; ++kk){
        short8 a1f[M_REP], a2f[M_REP], bfr[N_REP];
        const int lco = kk * 32 + (lane >> 4) * 8;
        const int lro = lane & 15;
        #pragma unroll
        for (int m = 0; m < M_REP; ++m){
          int r = wr * WM + m * 16 + lro;
          a1f[m] = *(const short8*)(ldsA1 + ldsx(r, lco));
          if (DUAL) a2f[m] = *(const short8*)(ldsA2 + ldsx(r, lco));
        }
        #pragma unroll
        for (int n = 0; n < N_REP; ++n){
          int cN = wc * WN + n * 16 + lro;
          bfr[n] = *(const short8*)(ldsB + ldsx(cN, lco));
        }
        #pragma unroll
        for (int m = 0; m < M_REP; ++m){
          #pragma unroll
          for (int n = 0; n < N_REP; ++n){
            acc1[m][n] = __builtin_amdgcn_mfma_f32_16x16x32_bf16(a1f[m], bfr[n], acc1[m][n], 0, 0, 0);
            if (DUAL)
              acc2[m][n] = __builtin_amdgcn_mfma_f32_16x16x32_bf16(a2f[m], bfr[n], acc2[m][n], 0, 0, 0);
          }
        }
      }
    };

    if constexpr (PIPE == 1){
      do_stage(0, 0);
      do_stage(1, 1);
      for (int ks = 0; ks < NK - 2; ++ks){
        wait_vmcnt<CH_PW>();
        __builtin_amdgcn_s_barrier();
        compute(ks & 1);
        asm volatile("s_waitcnt lgkmcnt(0)" ::: "memory");
        __builtin_amdgcn_s_barrier();
        do_stage(ks & 1, ks + 2);
      }
      wait_vmcnt<CH_PW>();
      __builtin_amdgcn_s_barrier();
      compute(NK & 1);
      wait_vmcnt<0>();
      __builtin_amdgcn_s_barrier();
      compute((NK - 1) & 1);
    } else {
      for (int ks = 0; ks < NK; ++ks){
        do_stage(0, ks);
        __syncthreads();
        compute(0);
        __syncthreads();
      }
    }
  }

  // C/D layout (m89-verified): col = lane&15, row = (lane>>4)*4 + reg
  const int rbase = (lane >> 4) * 4;
  const int cbase = lane & 15;
  if (EPI <= 1){
    #pragma unroll
    for (int m = 0; m < M_REP; ++m){
      #pragma unroll
      for (int n = 0; n < N_REP; ++n){
        #pragma unroll
        for (int j = 0; j < 4; ++j){
          const int R = m0 + wr * WM + m * 16 + rbase + j;
          const int C = n0 + wc * WN + n * 16 + cbase;
          const size_t idx = (size_t)R * HIDX + C;
          float a = acc1[m][n][j];
          if (EPI == 0){
            out1[idx] = f2bf_bits(a);
          } else {
            float z = a + bias[C] + tval * w1trow[C];
            float h = fast_tanh(z);
            out1[idx] = f2bf_bits(h);
            float d = bf2f_bits(dz1[idx]);
            out2[idx] = f2bf_bits(fmaf(-h, h, 1.0f) * d);   // dh1
          }
        }
      }
    }
  } else if (EPI == 2){
    // h2 = tanh(acc1+b2) stored; dh2 = (1-h2^2)*acc2 never stored;
    // trace partial Σ_C dh2·g -> atomicAdd into ljt
    #pragma unroll
    for (int m = 0; m < M_REP; ++m){
      #pragma unroll
      for (int j = 0; j < 4; ++j){
        const int R = m0 + wr * WM + m * 16 + rbase + j;
        float psum = 0.0f;
        #pragma unroll
        for (int n = 0; n < N_REP; ++n){
          const int C = n0 + wc * WN + n * 16 + cbase;
          const size_t idx = (size_t)R * HIDX + C;
          float h = fast_tanh(acc1[m][n][j] + bias[C]);
          out1[idx] = f2bf_bits(h);
          float dh2 = fmaf(-h, h, 1.0f) * acc2[m][n][j];
          psum += dh2 * bf2f_bits(gtr[idx]);
        }
        #pragma unroll
        for (int off = 1; off < 16; off <<= 1) psum += __shfl_xor(psum, off, 64);
        if (cbase == 0) atomicAdd(&ljt[R], wdt6 * psum);
      }
    }
  } else {
    // EPI==3: v = acc1 + b3; RK4 state update
    #pragma unroll
    for (int m = 0; m < M_REP; ++m){
      #pragma unroll
      for (int n = 0; n < N_REP; ++n){
        #pragma unroll
        for (int j = 0; j < 4; ++j){
          const int R = m0 + wr * WM + m * 16 + rbase + j;
          const int C = n0 + wc * WN + n * 16 + cbase;
          const size_t idx = (size_t)R * DIMX + C;
          float v = acc1[m][n][j] + bias[C];
          float xtv = xt[idx];
          if (rk == 0){
            vacc[idx] = v;
            xcbf[idx] = f2bf_bits(xtv + 0.5f * DTC * v);
          } else if (rk == 1){
            vacc[idx] += 2.0f * v;
            xcbf[idx] = f2bf_bits(xtv + 0.5f * DTC * v);
          } else if (rk == 2){
            vacc[idx] += 2.0f * v;
            xcbf[idx] = f2bf_bits(xtv + DTC * v);
          } else {
            float xtn = xtv + (DTC / 6.0f) * (vacc[idx] + v);
            xt[idx] = xtn;
            xcbf[idx] = f2bf_bits(xtn);
          }
        }
      }
    }
  }
}

// --------------- final: logprob = -0.5*||xt||^2 - const - ljt ---------------
__global__ void final_kernel(const float* __restrict__ xt, const float* __restrict__ ljt,
                             float* __restrict__ out){
  const int row = blockIdx.x * 4 + (threadIdx.x >> 6);
  const int lane = threadIdx.x & 63;
  const float4 xv = *(const float4*)(xt + (size_t)row * 256 + lane * 4);
  float s = xv.x * xv.x + xv.y * xv.y + xv.z * xv.z + xv.w * xv.w;
  #pragma unroll
  for (int off = 32; off; off >>= 1) s += __shfl_xor(s, off, 64);
  if (lane == 0) out[row] = -0.5f * s - 235.2482645f - ljt[row];
}

extern "C" void kernel_launch(void* const* d_in, const int* in_sizes, int n_in,
                              void* d_out, int out_size, void* d_ws, size_t ws_size,
                              hipStream_t stream){
  (void)in_sizes; (void)n_in; (void)out_size; (void)ws_size;
  const float* x    = (const float*)d_in[0];
  const float* W1   = (const float*)d_in[1];
  const float* b1   = (const float*)d_in[2];
  const float* W2   = (const float*)d_in[3];
  const float* b2   = (const float*)d_in[4];
  const float* W3   = (const float*)d_in[5];
  const float* b3   = (const float*)d_in[6];
  const float* proj = (const float*)d_in[7];

  size_t off = 0;
  char* wsb = (char*)d_ws;
  auto carve = [&](size_t n) -> char* {
    char* p = wsb + off; off += (n + 255) & ~(size_t)255; return p;
  };
  ushort_t* W1at     = (ushort_t*)carve((size_t)1024 * 256 * 2);
  ushort_t* W2t      = (ushort_t*)carve((size_t)1024 * 1024 * 2);
  ushort_t* W3t      = (ushort_t*)carve((size_t)256 * 1024 * 2);
  ushort_t* W3n      = (ushort_t*)carve((size_t)1024 * 256 * 2);
  ushort_t* noise_bf = (ushort_t*)carve((size_t)NB * 256 * 2);
  ushort_t* dz1      = (ushort_t*)carve((size_t)NB * 1024 * 2);
  ushort_t* gtr      = (ushort_t*)carve((size_t)NB * 1024 * 2);
  float*    xt       = (float*)carve((size_t)NB * 256 * 4);
  ushort_t* xcbf     = (ushort_t*)carve((size_t)NB * 256 * 2);
  float*    vacc     = (float*)carve((size_t)NB * 256 * 4);
  float*    ljt      = (float*)carve((size_t)NB * 4);
  ushort_t* h1       = (ushort_t*)carve((size_t)NB * 1024 * 2);
  ushort_t* dh1      = (ushort_t*)carve((size_t)NB * 1024 * 2);
  ushort_t* h2       = (ushort_t*)carve((size_t)NB * 1024 * 2);

  prep_weights<<<7168, 256, 0, stream>>>(W1, W2, W3, W1at, W2t, W3t, W3n);
  noise_init<<<NB / 8, 256, 0, stream>>>(x, proj, noise_bf, xt, xcbf, ljt);

  // dz1 = noise @ W1[:256,:]   (constant across all 40 dyn evals)
  gemm_kernel<256, 256, 2, 256, 0, 0, 0><<<dim3(NB / 256, 4), 512, 0, stream>>>(
      noise_bf, nullptr, W1at, dz1, nullptr, nullptr, nullptr, 0.f,
      nullptr, nullptr, nullptr, nullptr, nullptr, nullptr, 0.f, 0);
  // g = noise @ W3^T           (constant; trace = Σ dh2·g, kills L3 tangent)
  gemm_kernel<256, 256, 2, 256, 0, 0, 0><<<dim3(NB / 256, 4), 512, 0, stream>>>(
      noise_bf, nullptr, W3n, gtr, nullptr, nullptr, nullptr, 0.f,
      nullptr, nullptr, nullptr, nullptr, nullptr, nullptr, 0.f, 0);

  const float toff[4] = {0.0f, -0.05f, -0.05f, -0.1f};
  const float wst[4]  = {1.0f, 2.0f, 2.0f, 1.0f};
  for (int k = 0; k < 10; ++k){
    float t = 1.0f - 0.1f * (float)k;
    for (int s = 0; s < 4; ++s){
      // L1: h1 = tanh(z1); dh1 = (1-h1^2)*dz1  (dh1 materialized — r6 lesson)
      gemm_kernel<256, 256, 2, 256, 0, 1, 0><<<dim3(NB / 256, 4), 512, 0, stream>>>(
          xcbf, nullptr, W1at, h1, dh1, b1, W1 + 256 * 1024, t + toff[s],
          dz1, nullptr, nullptr, nullptr, nullptr, nullptr, 0.f, 0);
      // L2 (dual; PIPE=3 occupancy experiment: BK=32, wave-tile 32x64,
      // 48KB LDS, launch_bounds(512,4) -> 2 blocks/CU): h2 + fused trace
      gemm_kernel<128, 128, 4, 1024, 1, 2, 3><<<dim3(NB / 128, 8), 512, 0, stream>>>(
          h1, dh1, W2t, h2, nullptr, b2, nullptr, 0.f,
          nullptr, gtr, nullptr, nullptr, nullptr, ljt, wst[s] * (DTC / 6.0f), 0);
      // L3 (single): v = h2@W3 + b3; RK4 state update
      gemm_kernel<128, 128, 4, 1024, 0, 3, 0><<<dim3(NB / 128, 2), 512, 0, stream>>>(
          h2, nullptr, W3t, nullptr, nullptr, b3, nullptr, 0.f,
          nullptr, nullptr, xt, vacc, xcbf, nullptr, 0.f, s);
    }
  }
  final_kernel<<<NB / 4, 256, 0, stream>>>(xt, ljt, (float*)d_out);
}

// Round 12
// 5604.139 us; speedup vs baseline: 1.0371x; 1.0371x over previous
//
#include <hip/hip_runtime.h>
#include <stdint.h>
#include <stddef.h>

typedef unsigned short ushort_t;
typedef float f32x4 __attribute__((ext_vector_type(4)));
typedef short short8 __attribute__((ext_vector_type(8)));

#define NB 16384
#define DIMX 256
#define HIDX 1024
#define DTC (-0.1f)

__device__ __forceinline__ unsigned short f2bf_bits(float f){
  unsigned int u = __float_as_uint(f);
  unsigned int r = (u + 0x7FFFu + ((u >> 16) & 1u)) >> 16;
  return (unsigned short)r;
}
__device__ __forceinline__ float bf2f_bits(unsigned short s){
  return __uint_as_float(((unsigned int)s) << 16);
}
__device__ __forceinline__ float fast_tanh(float x){
  float a = fabsf(x);
  float e = __expf(a + a);
  float r = 1.0f - 2.0f / (e + 1.0f);
  return copysignf(r, x);
}
__device__ __forceinline__ void gload16(const void* g, void* l){
  __builtin_amdgcn_global_load_lds(
      (const __attribute__((address_space(1))) void*)g,
      (__attribute__((address_space(3))) void*)l, 16, 0, 0);
}
// counted vmcnt wait (T4) — literal immediates via if-constexpr table
template<int N> __device__ __forceinline__ void wait_vmcnt(){
  if constexpr (N == 0)      asm volatile("s_waitcnt vmcnt(0)" ::: "memory");
  else if constexpr (N == 4) asm volatile("s_waitcnt vmcnt(4)" ::: "memory");
  else if constexpr (N == 6) asm volatile("s_waitcnt vmcnt(6)" ::: "memory");
  else if constexpr (N == 8) asm volatile("s_waitcnt vmcnt(8)" ::: "memory");
  else static_assert(N == 0, "unsupported vmcnt");
}
// T2 swizzle, 64-col (128B) rows. LDS[r*64 + (c ^ ((r&7)<<3))] = elem (r,c).
__device__ __forceinline__ int ldsx(int r, int c){
  return r * 64 + (c ^ ((r & 7) << 3));
}

// -------- weight prep: fp32 -> bf16; transposed [N][K] layouts + W3n --------
__global__ void prep_weights(const float* __restrict__ W1, const float* __restrict__ W2,
                             const float* __restrict__ W3,
                             ushort_t* __restrict__ W1at, ushort_t* __restrict__ W2t,
                             ushort_t* __restrict__ W3t, ushort_t* __restrict__ W3n){
  int i = blockIdx.x * blockDim.x + threadIdx.x;
  const int T1 = 1024 * 256, T2 = 1024 * 1024, T3 = 256 * 1024, T4 = 1024 * 256;
  if (i < T1){
    int n = i >> 8, k = i & 255;                 // W1at[n][k] = W1[k][n]
    W1at[i] = f2bf_bits(W1[k * 1024 + n]);
  } else if (i < T1 + T2){
    int j = i - T1; int n = j >> 10, k = j & 1023; // W2t[n][k] = W2[k][n]
    W2t[j] = f2bf_bits(W2[k * 1024 + n]);
  } else if (i < T1 + T2 + T3){
    int j = i - T1 - T2; int n = j >> 10, k = j & 1023; // W3t[n][k] = W3[k][n]
    W3t[j] = f2bf_bits(W3[k * 256 + n]);
  } else if (i < T1 + T2 + T3 + T4){
    int j = i - T1 - T2 - T3;                    // W3n[h][d] = W3[h][d] (g-GEMM B)
    W3n[j] = f2bf_bits(W3[j]);
  }
}

// ----------- noise = sin(1000*(x@proj))*sqrt2 (fp32!), state init -----------
__global__ void noise_init(const float* __restrict__ x, const float* __restrict__ proj,
                           ushort_t* __restrict__ noise_bf,
                           float* __restrict__ xt, ushort_t* __restrict__ xcbf,
                           float* __restrict__ ljt){
  const int r0 = blockIdx.x * 8;
  const int j = threadIdx.x;   // 256 threads = one output col each
  __shared__ float xrow[8][256];
  #pragma unroll
  for (int r = 0; r < 8; ++r) xrow[r][j] = x[(size_t)(r0 + r) * 256 + j];
  __syncthreads();
  float s[8] = {0.f,0.f,0.f,0.f,0.f,0.f,0.f,0.f};
  for (int k = 0; k < 256; ++k){
    float p = proj[k * 256 + j];
    #pragma unroll
    for (int r = 0; r < 8; ++r) s[r] = fmaf(xrow[r][k], p, s[r]);
  }
  #pragma unroll
  for (int r = 0; r < 8; ++r){
    float nz = sinf(s[r] * 1000.0f) * 1.41421356237f;
    size_t idx = (size_t)(r0 + r) * 256 + j;
    noise_bf[idx] = f2bf_bits(nz);
    float xv = xrow[r][j];
    xt[idx] = xv;
    xcbf[idx] = f2bf_bits(xv);
  }
  if (j < 8) ljt[r0 + j] = 0.0f;
}

// ---- GEMM template. PIPE=0: simple 2-barrier loop (memory-bound EPIs).
// PIPE=1: depth-2 prefetch dbuf, BK=64, counted vmcnt — the proven L2
// schedule (85µs, MfmaUtil 33%, 0 conflicts).
// C[M,N] = A[M,K] @ W[K,N], W stored transposed [N][K] bf16, A row-major bf16.
// 8 waves as WGM(M) x (8/WGM)(N).
// DUAL: 0 = single GEMM; 1 = dual (A2 staged from global, e.g. dh1).
// EPI: 0 = store bf16 (dz1/g); 1 = layer1 (tanh -> h1, (1-h^2)*dz1 -> dh1);
// 2 = layer2 (tanh -> h2 + fused trace into ljt); 3 = layer3 (RK4 update).
// L2 structure search is CLOSED (r8-r11): coarse phase-split 105µs (m196),
// fine 4-phase 111µs + vmcnt race (vmcnt covers only the issuing wave's own
// loads — reads must follow the post-vmcnt barrier), small-tile/4-waves-SIMD
// 88µs (occupancy doubled, MfmaUtil flat: LDS-pipe contention + 1.5x FETCH +
// conflicts). Dual-acc register wall: wave-tile 64x64 dual = 128 acc VGPRs
// => 2 waves/SIMD at the traffic-optimal 128x256 tile. Depth-2 dbuf wins.
// Other lessons: r3 = no pipe on memory-bound EPIs; r4/m141 = no
// sched_barrier(0); r6 = no in-K-loop tangent recompute.
template<int BM, int BN, int WGM, int K, int DUAL, int EPI, int PIPE>
__launch_bounds__(512, 2)
__global__ void gemm_kernel(const ushort_t* __restrict__ A1, const ushort_t* __restrict__ A2,
                            const ushort_t* __restrict__ Wt,
                            ushort_t* __restrict__ out1, ushort_t* __restrict__ out2,
                            const float* __restrict__ bias, const float* __restrict__ w1trow,
                            float tval,
                            const ushort_t* __restrict__ dz1,
                            const ushort_t* __restrict__ gtr,
                            float* __restrict__ xt, float* __restrict__ vacc,
                            ushort_t* __restrict__ xcbf,
                            float* __restrict__ ljt, float wdt6, int rk){
  constexpr int BK = 64;
  constexpr int WGN = 8 / WGM;
  constexpr int WM = BM / WGM, WN = BN / WGN;
  constexpr int M_REP = WM / 16, N_REP = WN / 16;
  constexpr int ATILES = DUAL ? 2 : 1;
  constexpr int CH_A = BM / 8;                 // 1KB chunks per A tile
  constexpr int CH_TOT = ATILES * CH_A + BN / 8;
  constexpr int CH_PW = CH_TOT / 8;            // chunks per wave per K-step
  constexpr int BUF_E = (ATILES * BM + BN) * BK;  // elements per LDS buffer
  constexpr int NBUF = PIPE ? 2 : 1;
  constexpr int NK = K / BK;
  static_assert(!PIPE || NK >= 2, "pipeline needs >=2 K-steps");

  __shared__ __align__(16) ushort_t lds[NBUF * BUF_E];

  const int m0 = blockIdx.x * BM;
  const int n0 = blockIdx.y * BN;
  const int tid = threadIdx.x;
  const int lane = tid & 63;
  const int wid = tid >> 6;
  const int wr = wid / WGN;
  const int wc = wid % WGN;

  f32x4 acc1[M_REP][N_REP] = {};
  f32x4 acc2[M_REP][N_REP] = {};

  // staging: lane l writes 16B to linear LDS slot l within its 1KB chunk;
  // the global SOURCE column is pre-swizzled so reads can use ldsx() (m173).
  const int srow = lane >> 3;                       // row-in-chunk == r&7
  const int scol = ((lane & 7) ^ srow) * 8;         // pre-swizzled source col

  // per-chunk global row base pointers (statically indexed -> registers)
  const ushort_t* srcb[CH_PW];
  #pragma unroll
  for (int c = 0; c < CH_PW; ++c){
    const int ch = wid * CH_PW + c;
    if (ch < CH_A)
      srcb[c] = A1 + (size_t)(m0 + ch * 8 + srow) * K + scol;
    else if (DUAL && ch < 2 * CH_A)
      srcb[c] = A2 + (size_t)(m0 + (ch - CH_A) * 8 + srow) * K + scol;
    else
      srcb[c] = Wt + (size_t)(n0 + (ch - ATILES * CH_A) * 8 + srow) * K + scol;
  }

  auto do_stage = [&](int buf, int ks){
    ushort_t* dst = lds + buf * BUF_E + (wid * CH_PW) * 512;
    const int k0 = ks * BK;
    #pragma unroll
    for (int c = 0; c < CH_PW; ++c)
      gload16(srcb[c] + k0, dst + c * 512);
  };

  auto compute = [&](int buf){
    const ushort_t* ldsA1 = lds + buf * BUF_E;
    const ushort_t* ldsA2 = ldsA1 + BM * BK;
    const ushort_t* ldsB  = ldsA1 + ATILES * BM * BK;
    #pragma unroll
    for (int kk = 0; kk < 2; ++kk){
      short8 a1f[M_REP], a2f[M_REP], bfr[N_REP];
      const int lco = kk * 32 + (lane >> 4) * 8;
      const int lro = lane & 15;
      #pragma unroll
      for (int m = 0; m < M_REP; ++m){
        int r = wr * WM + m * 16 + lro;
        a1f[m] = *(const short8*)(ldsA1 + ldsx(r, lco));
        if (DUAL) a2f[m] = *(const short8*)(ldsA2 + ldsx(r, lco));
      }
      #pragma unroll
      for (int n = 0; n < N_REP; ++n){
        int cN = wc * WN + n * 16 + lro;
        bfr[n] = *(const short8*)(ldsB + ldsx(cN, lco));
      }
      #pragma unroll
      for (int m = 0; m < M_REP; ++m){
        #pragma unroll
        for (int n = 0; n < N_REP; ++n){
          acc1[m][n] = __builtin_amdgcn_mfma_f32_16x16x32_bf16(a1f[m], bfr[n], acc1[m][n], 0, 0, 0);
          if (DUAL)
            acc2[m][n] = __builtin_amdgcn_mfma_f32_16x16x32_bf16(a2f[m], bfr[n], acc2[m][n], 0, 0, 0);
        }
      }
    }
  };

  if constexpr (PIPE){
    // Pipelined K-loop: depth-2 prefetch, counted vmcnt (T3/T4).
    // Invariant at iter ks: newest CH_PW outstanding VMEM ops = tile ks+1's
    // loads, so vmcnt(CH_PW) == "tile ks landed"; the barrier AFTER the wait
    // makes it block-wide — reads only happen after that barrier.
    do_stage(0, 0);
    do_stage(1, 1);
    for (int ks = 0; ks < NK - 2; ++ks){
      wait_vmcnt<CH_PW>();
      __builtin_amdgcn_s_barrier();
      compute(ks & 1);
      // drain my ds_reads before signaling buffer free; register-only MFMAs
      // remain free to sink past barrier-2 (that sink IS the pipeline gain).
      asm volatile("s_waitcnt lgkmcnt(0)" ::: "memory");
      __builtin_amdgcn_s_barrier();          // everyone done reading buf ks&1
      do_stage(ks & 1, ks + 2);              // safe to overwrite it now
    }
    wait_vmcnt<CH_PW>();
    __builtin_amdgcn_s_barrier();
    compute(NK & 1);                         // tile NK-2 in buf (NK-2)&1
    wait_vmcnt<0>();
    __builtin_amdgcn_s_barrier();
    compute((NK - 1) & 1);                   // last tile
  } else {
    // Simple 2-barrier loop (round-2 structure) — best for memory-bound EPIs.
    for (int ks = 0; ks < NK; ++ks){
      do_stage(0, ks);
      __syncthreads();   // compiler drains vmcnt(0) before barrier
      compute(0);
      __syncthreads();
    }
  }

  // C/D layout (m89-verified): col = lane&15, row = (lane>>4)*4 + reg
  const int rbase = (lane >> 4) * 4;
  const int cbase = lane & 15;
  if (EPI <= 1){
    #pragma unroll
    for (int m = 0; m < M_REP; ++m){
      #pragma unroll
      for (int n = 0; n < N_REP; ++n){
        #pragma unroll
        for (int j = 0; j < 4; ++j){
          const int R = m0 + wr * WM + m * 16 + rbase + j;
          const int C = n0 + wc * WN + n * 16 + cbase;
          const size_t idx = (size_t)R * HIDX + C;
          float a = acc1[m][n][j];
          if (EPI == 0){
            out1[idx] = f2bf_bits(a);
          } else {
            float z = a + bias[C] + tval * w1trow[C];
            float h = fast_tanh(z);
            out1[idx] = f2bf_bits(h);
            float d = bf2f_bits(dz1[idx]);
            out2[idx] = f2bf_bits(fmaf(-h, h, 1.0f) * d);   // dh1
          }
        }
      }
    }
  } else if (EPI == 2){
    // h2 = tanh(acc1+b2) stored; dh2 = (1-h2^2)*acc2 never stored;
    // trace partial Σ_C dh2·g -> atomicAdd into ljt
    #pragma unroll
    for (int m = 0; m < M_REP; ++m){
      #pragma unroll
      for (int j = 0; j < 4; ++j){
        const int R = m0 + wr * WM + m * 16 + rbase + j;
        float psum = 0.0f;
        #pragma unroll
        for (int n = 0; n < N_REP; ++n){
          const int C = n0 + wc * WN + n * 16 + cbase;
          const size_t idx = (size_t)R * HIDX + C;
          float h = fast_tanh(acc1[m][n][j] + bias[C]);
          out1[idx] = f2bf_bits(h);
          float dh2 = fmaf(-h, h, 1.0f) * acc2[m][n][j];
          psum += dh2 * bf2f_bits(gtr[idx]);
        }
        #pragma unroll
        for (int off = 1; off < 16; off <<= 1) psum += __shfl_xor(psum, off, 64);
        if (cbase == 0) atomicAdd(&ljt[R], wdt6 * psum);
      }
    }
  } else {
    // EPI==3: v = acc1 + b3; RK4 state update
    #pragma unroll
    for (int m = 0; m < M_REP; ++m){
      #pragma unroll
      for (int n = 0; n < N_REP; ++n){
        #pragma unroll
        for (int j = 0; j < 4; ++j){
          const int R = m0 + wr * WM + m * 16 + rbase + j;
          const int C = n0 + wc * WN + n * 16 + cbase;
          const size_t idx = (size_t)R * DIMX + C;
          float v = acc1[m][n][j] + bias[C];
          float xtv = xt[idx];
          if (rk == 0){
            vacc[idx] = v;
            xcbf[idx] = f2bf_bits(xtv + 0.5f * DTC * v);
          } else if (rk == 1){
            vacc[idx] += 2.0f * v;
            xcbf[idx] = f2bf_bits(xtv + 0.5f * DTC * v);
          } else if (rk == 2){
            vacc[idx] += 2.0f * v;
            xcbf[idx] = f2bf_bits(xtv + DTC * v);
          } else {
            float xtn = xtv + (DTC / 6.0f) * (vacc[idx] + v);
            xt[idx] = xtn;
            xcbf[idx] = f2bf_bits(xtn);
          }
        }
      }
    }
  }
}

// --------------- final: logprob = -0.5*||xt||^2 - const - ljt ---------------
__global__ void final_kernel(const float* __restrict__ xt, const float* __restrict__ ljt,
                             float* __restrict__ out){
  const int row = blockIdx.x * 4 + (threadIdx.x >> 6);
  const int lane = threadIdx.x & 63;
  const float4 xv = *(const float4*)(xt + (size_t)row * 256 + lane * 4);
  float s = xv.x * xv.x + xv.y * xv.y + xv.z * xv.z + xv.w * xv.w;
  #pragma unroll
  for (int off = 32; off; off >>= 1) s += __shfl_xor(s, off, 64);
  if (lane == 0) out[row] = -0.5f * s - 235.2482645f - ljt[row];
}

extern "C" void kernel_launch(void* const* d_in, const int* in_sizes, int n_in,
                              void* d_out, int out_size, void* d_ws, size_t ws_size,
                              hipStream_t stream){
  (void)in_sizes; (void)n_in; (void)out_size; (void)ws_size;
  const float* x    = (const float*)d_in[0];
  const float* W1   = (const float*)d_in[1];
  const float* b1   = (const float*)d_in[2];
  const float* W2   = (const float*)d_in[3];
  const float* b2   = (const float*)d_in[4];
  const float* W3   = (const float*)d_in[5];
  const float* b3   = (const float*)d_in[6];
  const float* proj = (const float*)d_in[7];

  size_t off = 0;
  char* wsb = (char*)d_ws;
  auto carve = [&](size_t n) -> char* {
    char* p = wsb + off; off += (n + 255) & ~(size_t)255; return p;
  };
  ushort_t* W1at     = (ushort_t*)carve((size_t)1024 * 256 * 2);
  ushort_t* W2t      = (ushort_t*)carve((size_t)1024 * 1024 * 2);
  ushort_t* W3t      = (ushort_t*)carve((size_t)256 * 1024 * 2);
  ushort_t* W3n      = (ushort_t*)carve((size_t)1024 * 256 * 2);
  ushort_t* noise_bf = (ushort_t*)carve((size_t)NB * 256 * 2);
  ushort_t* dz1      = (ushort_t*)carve((size_t)NB * 1024 * 2);
  ushort_t* gtr      = (ushort_t*)carve((size_t)NB * 1024 * 2);
  float*    xt       = (float*)carve((size_t)NB * 256 * 4);
  ushort_t* xcbf     = (ushort_t*)carve((size_t)NB * 256 * 2);
  float*    vacc     = (float*)carve((size_t)NB * 256 * 4);
  float*    ljt      = (float*)carve((size_t)NB * 4);
  ushort_t* h1       = (ushort_t*)carve((size_t)NB * 1024 * 2);
  ushort_t* dh1      = (ushort_t*)carve((size_t)NB * 1024 * 2);
  ushort_t* h2       = (ushort_t*)carve((size_t)NB * 1024 * 2);

  prep_weights<<<7168, 256, 0, stream>>>(W1, W2, W3, W1at, W2t, W3t, W3n);
  noise_init<<<NB / 8, 256, 0, stream>>>(x, proj, noise_bf, xt, xcbf, ljt);

  // dz1 = noise @ W1[:256,:]   (constant across all 40 dyn evals)
  gemm_kernel<256, 256, 2, 256, 0, 0, 0><<<dim3(NB / 256, 4), 512, 0, stream>>>(
      noise_bf, nullptr, W1at, dz1, nullptr, nullptr, nullptr, 0.f,
      nullptr, nullptr, nullptr, nullptr, nullptr, nullptr, 0.f, 0);
  // g = noise @ W3^T           (constant; trace = Σ dh2·g, kills L3 tangent)
  gemm_kernel<256, 256, 2, 256, 0, 0, 0><<<dim3(NB / 256, 4), 512, 0, stream>>>(
      noise_bf, nullptr, W3n, gtr, nullptr, nullptr, nullptr, 0.f,
      nullptr, nullptr, nullptr, nullptr, nullptr, nullptr, 0.f, 0);

  const float toff[4] = {0.0f, -0.05f, -0.05f, -0.1f};
  const float wst[4]  = {1.0f, 2.0f, 2.0f, 1.0f};
  for (int k = 0; k < 10; ++k){
    float t = 1.0f - 0.1f * (float)k;
    for (int s = 0; s < 4; ++s){
      // L1: h1 = tanh(z1); dh1 = (1-h1^2)*dz1  (dh1 materialized — r6 lesson)
      gemm_kernel<256, 256, 2, 256, 0, 1, 0><<<dim3(NB / 256, 4), 512, 0, stream>>>(
          xcbf, nullptr, W1at, h1, dh1, b1, W1 + 256 * 1024, t + toff[s],
          dz1, nullptr, nullptr, nullptr, nullptr, nullptr, 0.f, 0);
      // L2 (dual staged h1,dh1; PIPE=1 known-good): h2 + fused trace via gtr
      gemm_kernel<128, 256, 2, 1024, 1, 2, 1><<<dim3(NB / 128, 4), 512, 0, stream>>>(
          h1, dh1, W2t, h2, nullptr, b2, nullptr, 0.f,
          nullptr, gtr, nullptr, nullptr, nullptr, ljt, wst[s] * (DTC / 6.0f), 0);
      // L3 (single): v = h2@W3 + b3; RK4 state update
      gemm_kernel<128, 128, 4, 1024, 0, 3, 0><<<dim3(NB / 128, 2), 512, 0, stream>>>(
          h2, nullptr, W3t, nullptr, nullptr, b3, nullptr, 0.f,
          nullptr, nullptr, xt, vacc, xcbf, nullptr, 0.f, s);
    }
  }
  final_kernel<<<NB / 4, 256, 0, stream>>>(xt, ljt, (float*)d_out);
}